// Round 3
// baseline (99.225 us; speedup 1.0000x reference)
//
#include <hip/hip_runtime.h>
#include <cstdint>
#include <cstddef>

typedef __attribute__((ext_vector_type(4))) short short4v;
typedef __attribute__((ext_vector_type(8))) short short8v;
typedef __attribute__((ext_vector_type(4))) float floatx4;

#define LIN 568   // weight row length: 1 + 9*63

__device__ __forceinline__ short f32_to_bf16(float f) {
  unsigned u = __builtin_bit_cast(unsigned, f);
  u += 0x7fffu + ((u >> 16) & 1u);   // RNE (inputs finite)
  return (short)(u >> 16);
}
__device__ __forceinline__ float bf16_to_f32(short s) {
  return __builtin_bit_cast(float, ((unsigned)(unsigned short)s) << 16);
}

// Pack weight into MFMA-B-fragment-major order (bf16):
//   wfragg[step*2048 + nb*512 + lane*8 + j]
//     = W[n = nb*16 + (lane&15)][k = tap*64 + half*32 + (lane>>4)*8 + j]
// step = tap*2 + half; the c==0 column is zeroed (time feature is a rank-1
// epilogue term).
__global__ void prep_weight(const float* __restrict__ w, short* __restrict__ wfragg) {
  int i = blockIdx.x * 256 + threadIdx.x;   // 0 .. 36863
  if (i >= 9 * 2 * 4 * 64 * 8) return;
  int j    = i & 7;
  int lane = (i >> 3) & 63;
  int nb   = (i >> 9) & 3;
  int half = (i >> 11) & 1;
  int tap  = i >> 12;
  int n = nb * 16 + (lane & 15);
  int c = half * 32 + ((lane >> 4) << 3) + j;
  float v = (c == 0) ? 0.0f : w[n * LIN + 1 + tap * 63 + (c - 1)];
  wfragg[i] = f32_to_bf16(v);
}

// Block: 256 threads = 4 waves, strip of 4 output rows (256 px) x 65 out-ch.
// Wave: 1 row = 64 px = 4 m-blocks x 4 n-blocks of 16x16x32 bf16 MFMA.
// One barrier; A from LDS, B from global (L2-resident fragment-packed weight)
// with distance-3 register prefetch issued starting BEFORE the barrier.
__launch_bounds__(256, 2)
__global__ void lconv_main(const float* __restrict__ x, const float* __restrict__ w,
                           const float* __restrict__ bias, const short* __restrict__ wfragg,
                           float* __restrict__ out) {
  __shared__ short xt[6 * 66 * 72];   // 57024 B : rows h0-1..h0+4, cols -1..64, ch stride 72

  const int tid = threadIdx.x;
  const int bb = blockIdx.x >> 4;          // batch 0..31
  const int h0 = (blockIdx.x & 15) << 2;   // first output row of 4-row strip
  const float* xb = x + (size_t)bb * (64 * 64 * 64);

  const int lane = tid & 63;
  const int l15 = lane & 15;
  const int q = lane >> 4;
  const int wv = tid >> 6;   // wave id = strip row

  // ---- early issue: B fragments for steps 0..2 + epilogue constants ----
  const short* wfl = wfragg + lane * 8;
  short8v b0[4], b1[4], b2[4];
#pragma unroll
  for (int nb = 0; nb < 4; ++nb) {
    b0[nb] = *(const short8v*)(wfl + 0 * 2048 + nb * 512);
    b1[nb] = *(const short8v*)(wfl + 1 * 2048 + nb * 512);
    b2[nb] = *(const short8v*)(wfl + 2 * 2048 + nb * 512);
  }
  float bj[4], w0j[4];
#pragma unroll
  for (int nb = 0; nb < 4; ++nb) {
    int n = nb * 16 + l15;
    bj[nb] = bias[n];
    w0j[nb] = w[n * LIN];   // weight[:,0] fp32
  }

  // ---- stage x rows h0-1 .. h0+4 into xt cols 1..64 (fp32 -> bf16) ----
#pragma unroll
  for (int i = 0; i < 12; ++i) {
    int idx = i * 256 + tid;       // 6 rows x 64 cols x 8 ch8-groups
    int row = idx >> 9;            // 0..5
    int rem = idx & 511;
    int col = rem >> 3;            // 0..63
    int ch8 = (rem & 7) << 3;      // 0,8,..,56
    int h = h0 - 1 + row;
    float4 v0 = {0.f, 0.f, 0.f, 0.f}, v1 = {0.f, 0.f, 0.f, 0.f};
    if ((unsigned)h < 64u) {
      const float* p = xb + ((h * 64 + col) * 64 + ch8);
      v0 = *(const float4*)p;
      v1 = *(const float4*)(p + 4);
    }
    short8v o;
    o[0] = f32_to_bf16(v0.x); o[1] = f32_to_bf16(v0.y);
    o[2] = f32_to_bf16(v0.z); o[3] = f32_to_bf16(v0.w);
    o[4] = f32_to_bf16(v1.x); o[5] = f32_to_bf16(v1.y);
    o[6] = f32_to_bf16(v1.z); o[7] = f32_to_bf16(v1.w);
    *(short8v*)&xt[(row * 66 + col + 1) * 72 + ch8] = o;
  }
  // zero spatial-pad cols 0 and 65
  if (tid < 96) {
    int r = tid >> 4;              // 0..5
    int cc = (tid >> 3) & 1;       // col 0 or 65
    int ch8 = (tid & 7) << 3;
    short8v z = {0, 0, 0, 0, 0, 0, 0, 0};
    *(short8v*)&xt[(r * 66 + cc * 65) * 72 + ch8] = z;
  }
  __syncthreads();   // the only block-wide barrier

  floatx4 acc[4][4];
#pragma unroll
  for (int mb = 0; mb < 4; ++mb)
#pragma unroll
    for (int nb = 0; nb < 4; ++nb) acc[mb][nb] = floatx4{0.f, 0.f, 0.f, 0.f};

#pragma unroll
  for (int step = 0; step < 18; ++step) {
    const int tap = step >> 1, half = step & 1;
    const int kh = tap / 3, kw = tap % 3;

    short8v bn[4];
    if (step + 3 < 18) {
#pragma unroll
      for (int nb = 0; nb < 4; ++nb)
        bn[nb] = *(const short8v*)(wfl + (step + 3) * 2048 + nb * 512);
    }

    const short* ab = &xt[((wv + kh) * 66 + kw + l15) * 72 + half * 32 + q * 8];
    short8v a[4];
#pragma unroll
    for (int mb = 0; mb < 4; ++mb)
      a[mb] = *(const short8v*)(ab + mb * 16 * 72);

#pragma unroll
    for (int mb = 0; mb < 4; ++mb) {
#pragma unroll
      for (int nb = 0; nb < 4; ++nb)
        acc[mb][nb] = __builtin_amdgcn_mfma_f32_16x16x32_bf16(a[mb], b0[nb], acc[mb][nb], 0, 0, 0);
    }
#pragma unroll
    for (int nb = 0; nb < 4; ++nb) { b0[nb] = b1[nb]; b1[nb] = b2[nb]; b2[nb] = bn[nb]; }
  }

  // ---- per-pixel time feature (this wave's row; lane <-> pixel col) ----
  float tres_v;
  {
    float ss = 0.f;
#pragma unroll
    for (int dh = 0; dh < 3; ++dh)
#pragma unroll
      for (int dw = 0; dw < 3; ++dw) {
        float tv = bf16_to_f32(xt[((wv + dh) * 66 + lane + dw) * 72]);
        tv = fmaxf(tv, 1.0f);
        ss += tv * tv;
      }
    tres_v = sqrtf(ss - 8.0f);
  }

  // ---- epilogue: bias + rank-1 time term, Lorentz norm, store ----
#pragma unroll
  for (int mb = 0; mb < 4; ++mb) {
#pragma unroll
    for (int r = 0; r < 4; ++r) {
      int pcol = mb * 16 + q * 4 + r;      // C/D row m = quad*4 + reg
      float tr = __shfl(tres_v, pcol);
      float v0 = acc[mb][0][r] + bj[0] + tr * w0j[0];
      float v1 = acc[mb][1][r] + bj[1] + tr * w0j[1];
      float v2 = acc[mb][2][r] + bj[2] + tr * w0j[2];
      float v3 = acc[mb][3][r] + bj[3] + tr * w0j[3];
      float ss = v0 * v0 + v1 * v1 + v2 * v2 + v3 * v3;
      ss += __shfl_xor(ss, 1);
      ss += __shfl_xor(ss, 2);
      ss += __shfl_xor(ss, 4);
      ss += __shfl_xor(ss, 8);
      float* ob = out + (size_t)((bb * 64 + h0 + wv) * 64 + pcol) * 65;
      if (l15 == 0) ob[0] = sqrtf(ss + 1.0f);
      ob[1 + l15]  = v0;
      ob[17 + l15] = v1;
      ob[33 + l15] = v2;
      ob[49 + l15] = v3;
    }
  }
}

extern "C" void kernel_launch(void* const* d_in, const int* in_sizes, int n_in,
                              void* d_out, int out_size, void* d_ws, size_t ws_size,
                              hipStream_t stream) {
  const float* x = (const float*)d_in[0];
  const float* w = (const float*)d_in[1];
  const float* b = (const float*)d_in[2];
  float* out = (float*)d_out;
  short* wfragg = (short*)d_ws;   // 73728 B fragment-packed bf16 weight

  prep_weight<<<144, 256, 0, stream>>>(w, wfragg);
  lconv_main<<<32 * 16, 256, 0, stream>>>(x, w, b, wfragg, out);
}

// Round 4
// 98.237 us; speedup vs baseline: 1.0101x; 1.0101x over previous
//
#include <hip/hip_runtime.h>
#include <cstdint>
#include <cstddef>

typedef __attribute__((ext_vector_type(4))) short short4v;
typedef __attribute__((ext_vector_type(8))) short short8v;
typedef __attribute__((ext_vector_type(4))) float floatx4;

#define LIN 568   // weight row length: 1 + 9*63

__device__ __forceinline__ short f32_to_bf16(float f) {
  unsigned u = __builtin_bit_cast(unsigned, f);
  u += 0x7fffu + ((u >> 16) & 1u);   // RNE (inputs finite)
  return (short)(u >> 16);
}
__device__ __forceinline__ float bf16_to_f32(short s) {
  return __builtin_bit_cast(float, ((unsigned)(unsigned short)s) << 16);
}

// Pack weight into MFMA-B-fragment-major order (bf16):
//   wfragg[step*2048 + nb*512 + lane*8 + j]
//     = W[n = nb*16 + (lane&15)][k = tap*64 + half*32 + (lane>>4)*8 + j]
// step = tap*2 + half; c==0 column zeroed (time feature is rank-1 epilogue).
__global__ void prep_weight(const float* __restrict__ w, short* __restrict__ wfragg) {
  int i = blockIdx.x * 256 + threadIdx.x;   // 0 .. 36863
  if (i >= 9 * 2 * 4 * 64 * 8) return;
  int j    = i & 7;
  int lane = (i >> 3) & 63;
  int nb   = (i >> 9) & 3;
  int half = (i >> 11) & 1;
  int tap  = i >> 12;
  int n = nb * 16 + (lane & 15);
  int c = half * 32 + ((lane >> 4) << 3) + j;
  float v = (c == 0) ? 0.0f : w[n * LIN + 1 + tap * 63 + (c - 1)];
  wfragg[i] = f32_to_bf16(v);
}

// Block: 256 threads = 4 waves, strip of 4 output rows (256 px) x 65 out-ch.
// Wave: 1 row = 64 px = 4 m-blocks x 4 n-blocks of 16x16x32 bf16 MFMA.
// Two-phase pipeline: stage LDS rows 0..3 -> barrier -> {stage rows 4..5
// overlapped with kh=0 compute (steps 0..5)} -> barrier -> steps 6..17.
__launch_bounds__(256, 2)
__global__ void lconv_main(const float* __restrict__ x, const float* __restrict__ w,
                           const float* __restrict__ bias, const short* __restrict__ wfragg,
                           float* __restrict__ out) {
  __shared__ short xt[6 * 66 * 72];   // 57024 B : rows h0-1..h0+4, cols -1..64, ch stride 72

  const int tid = threadIdx.x;
  const int bb = blockIdx.x >> 4;          // batch 0..31
  const int h0 = (blockIdx.x & 15) << 2;   // first output row of 4-row strip
  const float* xb = x + (size_t)bb * (64 * 64 * 64);

  const int lane = tid & 63;
  const int l15 = lane & 15;
  const int q = lane >> 4;
  const int wv = tid >> 6;   // wave id = strip row

  // ---- early issue: B fragments for steps 0..2 + epilogue constants ----
  const short* wfl = wfragg + lane * 8;
  short8v b0[4], b1[4], b2[4];
#pragma unroll
  for (int nb = 0; nb < 4; ++nb) {
    b0[nb] = *(const short8v*)(wfl + 0 * 2048 + nb * 512);
    b1[nb] = *(const short8v*)(wfl + 1 * 2048 + nb * 512);
    b2[nb] = *(const short8v*)(wfl + 2 * 2048 + nb * 512);
  }
  float bj[4], w0j[4];
#pragma unroll
  for (int nb = 0; nb < 4; ++nb) {
    int n = nb * 16 + l15;
    bj[nb] = bias[n];
    w0j[nb] = w[n * LIN];   // weight[:,0] fp32
  }

  // ---- phase-1 staging: LDS rows 0..3 (x rows h0-1..h0+2), cols 1..64 ----
#pragma unroll
  for (int i = 0; i < 8; ++i) {
    int idx = i * 256 + tid;       // 0..2047 : rows 0..3 x 64 cols x 8 ch8-groups
    int row = idx >> 9;
    int rem = idx & 511;
    int col = rem >> 3;
    int ch8 = (rem & 7) << 3;
    int h = h0 - 1 + row;
    float4 v0 = {0.f, 0.f, 0.f, 0.f}, v1 = {0.f, 0.f, 0.f, 0.f};
    if ((unsigned)h < 64u) {
      const float* p = xb + ((h * 64 + col) * 64 + ch8);
      v0 = *(const float4*)p;
      v1 = *(const float4*)(p + 4);
    }
    short8v o;
    o[0] = f32_to_bf16(v0.x); o[1] = f32_to_bf16(v0.y);
    o[2] = f32_to_bf16(v0.z); o[3] = f32_to_bf16(v0.w);
    o[4] = f32_to_bf16(v1.x); o[5] = f32_to_bf16(v1.y);
    o[6] = f32_to_bf16(v1.z); o[7] = f32_to_bf16(v1.w);
    *(short8v*)&xt[(row * 66 + col + 1) * 72 + ch8] = o;
  }
  if (tid < 64) {   // pads for rows 0..3, cols 0 and 65
    int r = tid >> 4;
    int cc = (tid >> 3) & 1;
    int ch8 = (tid & 7) << 3;
    short8v z = {0, 0, 0, 0, 0, 0, 0, 0};
    *(short8v*)&xt[(r * 66 + cc * 65) * 72 + ch8] = z;
  }
  __syncthreads();   // rows 0..3 visible -> kh=0 taps computable for all waves

  // ---- phase-2 staging: LDS rows 4..5 (x rows h0+3..h0+4) ----
#pragma unroll
  for (int i = 8; i < 12; ++i) {
    int idx = i * 256 + tid;       // 2048..3071 : rows 4..5
    int row = idx >> 9;
    int rem = idx & 511;
    int col = rem >> 3;
    int ch8 = (rem & 7) << 3;
    int h = h0 - 1 + row;
    float4 v0 = {0.f, 0.f, 0.f, 0.f}, v1 = {0.f, 0.f, 0.f, 0.f};
    if ((unsigned)h < 64u) {
      const float* p = xb + ((h * 64 + col) * 64 + ch8);
      v0 = *(const float4*)p;
      v1 = *(const float4*)(p + 4);
    }
    short8v o;
    o[0] = f32_to_bf16(v0.x); o[1] = f32_to_bf16(v0.y);
    o[2] = f32_to_bf16(v0.z); o[3] = f32_to_bf16(v0.w);
    o[4] = f32_to_bf16(v1.x); o[5] = f32_to_bf16(v1.y);
    o[6] = f32_to_bf16(v1.z); o[7] = f32_to_bf16(v1.w);
    *(short8v*)&xt[(row * 66 + col + 1) * 72 + ch8] = o;
  }
  if (tid < 32) {   // pads for rows 4..5
    int r = 4 + (tid >> 4);
    int cc = (tid >> 3) & 1;
    int ch8 = (tid & 7) << 3;
    short8v z = {0, 0, 0, 0, 0, 0, 0, 0};
    *(short8v*)&xt[(r * 66 + cc * 65) * 72 + ch8] = z;
  }

  floatx4 acc[4][4];
#pragma unroll
  for (int mb = 0; mb < 4; ++mb)
#pragma unroll
    for (int nb = 0; nb < 4; ++nb) acc[mb][nb] = floatx4{0.f, 0.f, 0.f, 0.f};

  auto do_step = [&](int step) {
    const int tap = step >> 1, half = step & 1;
    const int kh = tap / 3, kw = tap % 3;

    short8v bn[4];
    if (step + 3 < 18) {
#pragma unroll
      for (int nb = 0; nb < 4; ++nb)
        bn[nb] = *(const short8v*)(wfl + (step + 3) * 2048 + nb * 512);
    }

    const short* ab = &xt[((wv + kh) * 66 + kw + l15) * 72 + half * 32 + q * 8];
    short8v a[4];
#pragma unroll
    for (int mb = 0; mb < 4; ++mb)
      a[mb] = *(const short8v*)(ab + mb * 16 * 72);

#pragma unroll
    for (int mb = 0; mb < 4; ++mb) {
#pragma unroll
      for (int nb = 0; nb < 4; ++nb)
        acc[mb][nb] = __builtin_amdgcn_mfma_f32_16x16x32_bf16(a[mb], b0[nb], acc[mb][nb], 0, 0, 0);
    }
#pragma unroll
    for (int nb = 0; nb < 4; ++nb) { b0[nb] = b1[nb]; b1[nb] = b2[nb]; b2[nb] = bn[nb]; }
  };

  // kh=0 taps (steps 0..5) overlap the phase-2 staging above
#pragma unroll
  for (int step = 0; step < 6; ++step) do_step(step);

  __syncthreads();   // rows 4..5 visible

#pragma unroll
  for (int step = 6; step < 18; ++step) do_step(step);

  // ---- per-pixel time feature (this wave's row; lane <-> pixel col) ----
  float tres_v;
  {
    float ss = 0.f;
#pragma unroll
    for (int dh = 0; dh < 3; ++dh)
#pragma unroll
      for (int dw = 0; dw < 3; ++dw) {
        float tv = bf16_to_f32(xt[((wv + dh) * 66 + lane + dw) * 72]);
        tv = fmaxf(tv, 1.0f);
        ss += tv * tv;
      }
    tres_v = sqrtf(ss - 8.0f);
  }

  // ---- epilogue: bias + rank-1 time term, Lorentz norm, store ----
#pragma unroll
  for (int mb = 0; mb < 4; ++mb) {
#pragma unroll
    for (int r = 0; r < 4; ++r) {
      int pcol = mb * 16 + q * 4 + r;      // C/D row m = quad*4 + reg
      float tr = __shfl(tres_v, pcol);
      float v0 = acc[mb][0][r] + bj[0] + tr * w0j[0];
      float v1 = acc[mb][1][r] + bj[1] + tr * w0j[1];
      float v2 = acc[mb][2][r] + bj[2] + tr * w0j[2];
      float v3 = acc[mb][3][r] + bj[3] + tr * w0j[3];
      float ss = v0 * v0 + v1 * v1 + v2 * v2 + v3 * v3;
      ss += __shfl_xor(ss, 1);
      ss += __shfl_xor(ss, 2);
      ss += __shfl_xor(ss, 4);
      ss += __shfl_xor(ss, 8);
      float* ob = out + (size_t)((bb * 64 + h0 + wv) * 64 + pcol) * 65;
      if (l15 == 0) ob[0] = sqrtf(ss + 1.0f);
      ob[1 + l15]  = v0;
      ob[17 + l15] = v1;
      ob[33 + l15] = v2;
      ob[49 + l15] = v3;
    }
  }
}

extern "C" void kernel_launch(void* const* d_in, const int* in_sizes, int n_in,
                              void* d_out, int out_size, void* d_ws, size_t ws_size,
                              hipStream_t stream) {
  const float* x = (const float*)d_in[0];
  const float* w = (const float*)d_in[1];
  const float* b = (const float*)d_in[2];
  float* out = (float*)d_out;
  short* wfragg = (short*)d_ws;   // 73728 B fragment-packed bf16 weight

  prep_weight<<<144, 256, 0, stream>>>(w, wfragg);
  lconv_main<<<32 * 16, 256, 0, stream>>>(x, w, b, wfragg, out);
}